// Round 3
// baseline (869.560 us; speedup 1.0000x reference)
//
#include <hip/hip_runtime.h>
#include <hip/hip_bf16.h>

#define HID   256
#define NGATE 1024
#define INP   72
#define STEPS 8
#define TB    64
#define LDH   264   // h_lds row stride (bf16 elems): 256 + 8 pad
#define LDX   104   // x_lds row stride: 96 + 8 pad

// ---- weight-stream geometry -------------------------------------------------
// Per wave per step: 96 fragments x 512 bf16 (1 KB) in exact consumption order:
//   f =  0..63 : WHH  (f = kc*8 + q*2 + ct, kc<8)
//   f = 64..87 : WIH  (f = 64 + kc*8 + q*2 + ct, kc<3; K padded to 96, zeros)
//   f = 88..95 : WO   (f = 88 + kc; zero-padded for waves 5..7)
// 96 % RING == 0 -> ring slots realign every step; all offsets compile-time.
#define NFRAG 96
#define RING  12          // wave-private LDS ring slots (12 KB/wave, 96 KB total)
#define WSEQ  49152       // elems per wave sequence = 96*512
// ws layout (bf16 elem offsets)
#define OFF_WH2 393216    // init Wh, packed 16 frags/wave (ct*8+kc)
#define OFF_WC2 458752    // init Wc, same
#define N_ALL   524288    // = 1 MiB of bf16
#define OFF_BG_BYTES    1048576
#define OFF_STAGE_BYTES 1114112

typedef short  s8_t  __attribute__((ext_vector_type(8)));
typedef float  f4_t  __attribute__((ext_vector_type(4)));

static __device__ __forceinline__ unsigned short f2bf(float f) {
  unsigned int u = __float_as_uint(f);
  u = (u + 0x7FFFu + ((u >> 16) & 1u)) >> 16;   // RNE
  return (unsigned short)u;
}
static __device__ __forceinline__ float fast_rcp(float x) {
#if __has_builtin(__builtin_amdgcn_rcpf)
  return __builtin_amdgcn_rcpf(x);
#else
  return 1.f / x;
#endif
}
static __device__ __forceinline__ float sigm(float x) {
  return fast_rcp(1.f + __expf(-x));
}
static __device__ __forceinline__ float tanh_(float x) {
  float t = fminf(-2.f * x, 88.f);
  float e = __expf(t);
  return (1.f - e) * fast_rcp(1.f + e);
}

// wave-private ring ops: no barriers needed (each wave reads only its own slots)
#define ISSUE(F, S) __builtin_amdgcn_global_load_lds( \
    (const __attribute__((address_space(1))) unsigned int*)(const void*)(seq_l + (F) * 512), \
    (__attribute__((address_space(3))) unsigned int*)(void*)(ring_wr + (S) * 512), 16, 0, 0)
#define WAITV10() asm volatile("s_waitcnt vmcnt(10)" ::: "memory")
// raw barrier: drains LDS counters only; global_load_lds prefetches stay in flight
#define BAR() do { asm volatile("s_waitcnt lgkmcnt(0)" ::: "memory"); \
                   __builtin_amdgcn_s_barrier(); \
                   asm volatile("" ::: "memory"); } while (0)

__global__ void prep_kernel(const float* __restrict__ Wih, const float* __restrict__ Whh,
                            const float* __restrict__ bih, const float* __restrict__ bhh,
                            const float* __restrict__ Wh, const float* __restrict__ Wc,
                            const float* __restrict__ Wo,
                            unsigned short* __restrict__ wsh, float* __restrict__ bg) {
  int stride = gridDim.x * blockDim.x;
  for (int i = blockIdx.x * blockDim.x + threadIdx.x; i < N_ALL + NGATE; i += stride) {
    if (i < N_ALL) {
      float v = 0.f;
      if (i < OFF_WH2) {
        // per-wave fragment stream
        int w  = i / WSEQ;
        int r  = i - w * WSEQ;
        int f  = r >> 9;
        int e  = r & 511;
        int lane = e >> 3, j = e & 7;
        int lq = lane >> 4, ln = lane & 15;
        int kk = lq * 8 + j;
        if (f < 64) {                         // WHH
          int kc = f >> 3, t = f & 7, q = t >> 1, ct = t & 1;
          int g  = q * 256 + w * 32 + ct * 16 + ln;
          int k  = kc * 32 + kk;
          v = Whh[g * HID + k];
        } else if (f < 88) {                  // WIH (K padded to 96)
          int t2 = f - 64;
          int kc = t2 >> 3, t = t2 & 7, q = t >> 1, ct = t & 1;
          int g  = q * 256 + w * 32 + ct * 16 + ln;
          int k  = kc * 32 + kk;
          v = (k < INP) ? Wih[g * INP + k] : 0.f;
        } else {                              // WO (waves 5..7 padded with 0)
          int kc = f - 88;
          int c  = w * 16 + ln;
          int k  = kc * 32 + kk;
          v = (w < 5 && c < INP) ? Wo[c * HID + k] : 0.f;
        }
      } else {
        // init weights Wh / Wc: 16 frags per wave, fi = ct*8 + kc
        int base = (i < OFF_WC2) ? OFF_WH2 : OFF_WC2;
        const float* Wsrc = (i < OFF_WC2) ? Wh : Wc;
        int jj = i - base;
        int w  = jj >> 13;            // 8192 elems per wave
        int r  = jj & 8191;
        int fi = r >> 9;
        int e  = r & 511;
        int lane = e >> 3, j = e & 7;
        int lq = lane >> 4, ln = lane & 15;
        int ct = fi >> 3, kc = fi & 7;
        int c  = w * 32 + ct * 16 + ln;
        int k  = kc * 32 + lq * 8 + j;
        v = Wsrc[c * HID + k];
      }
      wsh[i] = f2bf(v);
    } else {
      int jb = i - N_ALL;
      bg[jb] = bih[jb] + bhh[jb];
    }
  }
}

// Block: 512 threads = 8 waves, TB=64 batch rows for the whole recurrence.
// Wave w owns gate cols [w*32, w*32+32) in each gate quadrant. Weights stream
// through a wave-private 12-slot LDS ring via global_load_lds with counted
// vmcnt(10): issue frag f+11, wait, ds_read frag f+1 (consumed next iter so
// LDS latency hides under this iter's MFMAs). No barriers guard the ring;
// block barriers are raw s_barrier + lgkmcnt(0) so prefetches fly across them.
template <int STAGED>
__global__ __launch_bounds__(512, 2) void lstm_kernel(
    const float* __restrict__ z, const unsigned short* __restrict__ wsh,
    const float* __restrict__ bg, const float* __restrict__ bh,
    const float* __restrict__ bc, const float* __restrict__ bo,
    float* __restrict__ out, float* __restrict__ stage, int NB) {
  __shared__ unsigned short h_lds[TB * LDH];
  __shared__ unsigned short x_lds[TB * LDX];
  __shared__ unsigned short ring[8 * RING * 512];   // 96 KB, wave-private slices

  const int tid  = threadIdx.x;
  const int w    = tid >> 6;     // wave 0..7
  const int lane = tid & 63;
  const int lq   = lane >> 4;
  const int ln   = lane & 15;
  const int rb   = blockIdx.x * TB;
  const int colh0 = w * 32 + ln;

  const unsigned short* seq_l  = wsh + w * WSEQ + lane * 8;       // per-lane global src
  unsigned short*       ring_wr = &ring[w * (RING * 512)];        // wave-uniform LDS dst
  const unsigned short* ring_rd = &ring[w * (RING * 512) + lane * 8];

  const unsigned short* wh_l = wsh + OFF_WH2 + w * 8192 + lane * 8;
  const unsigned short* wc_l = wsh + OFF_WC2 + w * 8192 + lane * 8;
  const unsigned short* h_rd = &h_lds[ln * LDH + lq * 8];
  const unsigned short* x_rd = &x_lds[ln * LDX + lq * 8];
  unsigned short*       h_wr = &h_lds[(lq * 4) * LDH + colh0];

  for (int i = tid; i < TB * LDX; i += 512) x_lds[i] = 0;

  // ---------------- init: h = z0@Wh^T + bh, c = z0@Wc^T + bc ----------------
  f4_t acc_h[4][2], acc_c[4][2];
  #pragma unroll
  for (int rt = 0; rt < 4; ++rt)
    #pragma unroll
    for (int ct = 0; ct < 2; ++ct) {
      acc_h[rt][ct] = {0.f, 0.f, 0.f, 0.f};
      acc_c[rt][ct] = {0.f, 0.f, 0.f, 0.f};
    }

  const float* z_l = z + (size_t)(rb + ln) * HID + lq * 8;

  #pragma unroll 2
  for (int kc = 0; kc < 8; ++kc) {
    s8_t a[4];
    #pragma unroll
    for (int rt = 0; rt < 4; ++rt) {
      f4_t v0 = *reinterpret_cast<const f4_t*>(z_l + rt * 16 * HID + kc * 32);
      f4_t v1 = *reinterpret_cast<const f4_t*>(z_l + rt * 16 * HID + kc * 32 + 4);
      s8_t av;
      av[0] = (short)f2bf(v0[0]); av[1] = (short)f2bf(v0[1]);
      av[2] = (short)f2bf(v0[2]); av[3] = (short)f2bf(v0[3]);
      av[4] = (short)f2bf(v1[0]); av[5] = (short)f2bf(v1[1]);
      av[6] = (short)f2bf(v1[2]); av[7] = (short)f2bf(v1[3]);
      a[rt] = av;
    }
    #pragma unroll
    for (int ct = 0; ct < 2; ++ct) {
      s8_t bhf = *reinterpret_cast<const s8_t*>(wh_l + (ct * 8 + kc) * 512);
      s8_t bcf = *reinterpret_cast<const s8_t*>(wc_l + (ct * 8 + kc) * 512);
      #pragma unroll
      for (int rt = 0; rt < 4; ++rt) {
        acc_h[rt][ct] = __builtin_amdgcn_mfma_f32_16x16x32_bf16(a[rt], bhf, acc_h[rt][ct], 0, 0, 0);
        acc_c[rt][ct] = __builtin_amdgcn_mfma_f32_16x16x32_bf16(a[rt], bcf, acc_c[rt][ct], 0, 0, 0);
      }
    }
  }

  // prologue: issue ring frags 0..10 (they land during writeback + barrier)
  #pragma unroll
  for (int p = 0; p <= 10; ++p) ISSUE(p, p);

  float c_reg[4][2][4];
  #pragma unroll
  for (int ct = 0; ct < 2; ++ct) {
    const float bhv = bh[colh0 + ct * 16];
    const float bcv = bc[colh0 + ct * 16];
    #pragma unroll
    for (int rt = 0; rt < 4; ++rt)
      #pragma unroll
      for (int r = 0; r < 4; ++r) {
        float hv = acc_h[rt][ct][r] + bhv;
        c_reg[rt][ct][r] = acc_c[rt][ct][r] + bcv;
        h_wr[(rt * 16 + r) * LDH + ct * 16] = f2bf(hv);
      }
  }

  float biasg[4][2];
  #pragma unroll
  for (int q = 0; q < 4; ++q)
    #pragma unroll
    for (int ct = 0; ct < 2; ++ct)
      biasg[q][ct] = bg[q * 256 + colh0 + ct * 16];

  const int colY = w * 16 + ln;            // y col, valid for waves 0..4
  float bov = 0.f;
  if (w < 5 && colY < INP) bov = bo[colY];

  BAR();

  WAITV10();
  s8_t bcur = *reinterpret_cast<const s8_t*>(ring_rd);   // frag 0, slot 0
  s8_t bnxt;

  for (int s = 0; s < STEPS; ++s) {
    f4_t acc[4][4][2];                     // [quadrant][row-tile][col-tile]
    #pragma unroll
    for (int q = 0; q < 4; ++q)
      #pragma unroll
      for (int rt = 0; rt < 4; ++rt)
        #pragma unroll
        for (int ct = 0; ct < 2; ++ct) {
          const float b = biasg[q][ct];
          acc[q][rt][ct] = {b, b, b, b};
        }

    // gates += h @ W_hh^T   (K = 256) : frags 0..63
    #pragma unroll
    for (int kc = 0; kc < 8; ++kc) {
      s8_t a[4];
      #pragma unroll
      for (int rt = 0; rt < 4; ++rt)
        a[rt] = *reinterpret_cast<const s8_t*>(h_rd + rt * 16 * LDH + kc * 32);
      #pragma unroll
      for (int q = 0; q < 4; ++q)
        #pragma unroll
        for (int ct = 0; ct < 2; ++ct) {
          const int f = kc * 8 + q * 2 + ct;
          ISSUE((f + 11) % NFRAG, (f + 11) % RING);
          WAITV10();
          bnxt = *reinterpret_cast<const s8_t*>(ring_rd + ((f + 1) % RING) * 512);
          #pragma unroll
          for (int rt = 0; rt < 4; ++rt)
            acc[q][rt][ct] = __builtin_amdgcn_mfma_f32_16x16x32_bf16(a[rt], bcur, acc[q][rt][ct], 0, 0, 0);
          bcur = bnxt;
        }
    }
    // gates += x @ W_ih^T   (K = 96 padded) : frags 64..87
    #pragma unroll
    for (int kc = 0; kc < 3; ++kc) {
      s8_t a[4];
      #pragma unroll
      for (int rt = 0; rt < 4; ++rt)
        a[rt] = *reinterpret_cast<const s8_t*>(x_rd + rt * 16 * LDX + kc * 32);
      #pragma unroll
      for (int q = 0; q < 4; ++q)
        #pragma unroll
        for (int ct = 0; ct < 2; ++ct) {
          const int f = 64 + kc * 8 + q * 2 + ct;
          ISSUE((f + 11) % NFRAG, (f + 11) % RING);
          WAITV10();
          bnxt = *reinterpret_cast<const s8_t*>(ring_rd + ((f + 1) % RING) * 512);
          #pragma unroll
          for (int rt = 0; rt < 4; ++rt)
            acc[q][rt][ct] = __builtin_amdgcn_mfma_f32_16x16x32_bf16(a[rt], bcur, acc[q][rt][ct], 0, 0, 0);
          bcur = bnxt;
        }
    }
    BAR();   // all h_lds/x_lds reads done

    // lane-local LSTM cell update; write new h (bf16) to LDS
    #pragma unroll
    for (int rt = 0; rt < 4; ++rt)
      #pragma unroll
      for (int ct = 0; ct < 2; ++ct)
        #pragma unroll
        for (int r = 0; r < 4; ++r) {
          float iv = sigm(acc[0][rt][ct][r]);
          float fv = sigm(acc[1][rt][ct][r]);
          float gv = tanh_(acc[2][rt][ct][r]);
          float ov = sigm(acc[3][rt][ct][r]);
          float cn = fv * c_reg[rt][ct][r] + iv * gv;
          c_reg[rt][ct][r] = cn;
          float hv = ov * tanh_(cn);
          h_wr[(rt * 16 + r) * LDH + ct * 16] = f2bf(hv);
        }
    BAR();   // new h visible to all waves

    // y = sigmoid(h_new @ Wo^T + bo) : frags 88..95 (waves 5..7 stream pad)
    {
      f4_t accy[4];
      #pragma unroll
      for (int rt = 0; rt < 4; ++rt) accy[rt] = {bov, bov, bov, bov};
      #pragma unroll
      for (int kc = 0; kc < 8; ++kc) {
        const int f = 88 + kc;
        ISSUE((f + 11) % NFRAG, (f + 11) % RING);
        WAITV10();
        bnxt = *reinterpret_cast<const s8_t*>(ring_rd + ((f + 1) % RING) * 512);
        if (w < 5) {
          #pragma unroll
          for (int rt = 0; rt < 4; ++rt) {
            s8_t a = *reinterpret_cast<const s8_t*>(h_rd + rt * 16 * LDH + kc * 32);
            accy[rt] = __builtin_amdgcn_mfma_f32_16x16x32_bf16(a, bcur, accy[rt], 0, 0, 0);
          }
        }
        bcur = bnxt;
      }
      if (w < 5 && colY < INP) {
        float* st_base;
        if (STAGED) {
          st_base = stage + (((size_t)s * NB + blockIdx.x) * TB + lq * 4) * INP + colY;
        } else {
          st_base = out + (size_t)(rb + lq * 4) * (STEPS * INP) + s * INP + colY;
        }
        unsigned short* x_wr = &x_lds[(lq * 4) * LDX + colY];
        #pragma unroll
        for (int rt = 0; rt < 4; ++rt)
          #pragma unroll
          for (int r = 0; r < 4; ++r) {
            float yv = sigm(accy[rt][r]);
            if (STAGED) {
              st_base[(size_t)(rt * 16 + r) * INP] = yv;
            } else {
              st_base[(size_t)(rt * 16 + r) * (STEPS * INP)] = yv;
            }
            x_wr[(rt * 16 + r) * LDX] = f2bf(yv);
          }
      }
    }
    BAR();   // x_lds writes done before next step's reads
  }
}

// stage[((s*NB + b)*TB + r)*72 + c]  ->  out[(b*TB + r)*576 + s*72 + c]
__global__ __launch_bounds__(512) void reorder_kernel(
    const float* __restrict__ stage, float* __restrict__ out, int NB) {
  const int lane = threadIdx.x & 63;
  const int row  = blockIdx.x * 8 + (threadIdx.x >> 6);   // global batch row
  const int b    = row >> 6;          // TB=64
  const int r    = row & 63;
  #pragma unroll
  for (int i = lane; i < STEPS * INP; i += 64) {
    int s = i / INP;
    int c = i - s * INP;
    out[(size_t)row * (STEPS * INP) + i] =
        stage[(((size_t)s * NB + b) * TB + r) * INP + c];
  }
}

extern "C" void kernel_launch(void* const* d_in, const int* in_sizes, int n_in,
                              void* d_out, int out_size, void* d_ws, size_t ws_size,
                              hipStream_t stream) {
  const float* z   = (const float*)d_in[0];
  const float* Wih = (const float*)d_in[1];
  const float* Whh = (const float*)d_in[2];
  const float* bih = (const float*)d_in[3];
  const float* bhh = (const float*)d_in[4];
  const float* Wh  = (const float*)d_in[5];
  const float* bh  = (const float*)d_in[6];
  const float* Wc  = (const float*)d_in[7];
  const float* bc  = (const float*)d_in[8];
  const float* Wo  = (const float*)d_in[9];
  const float* bo  = (const float*)d_in[10];
  float* out = (float*)d_out;

  unsigned short* wsh = (unsigned short*)d_ws;
  float* bg    = (float*)((char*)d_ws + OFF_BG_BYTES);
  float* stage = (float*)((char*)d_ws + OFF_STAGE_BYTES);

  const int B  = in_sizes[0] / HID;   // 32768
  const int NB = B / TB;              // 512

  hipLaunchKernelGGL(prep_kernel, dim3(512), dim3(256), 0, stream,
                     Wih, Whh, bih, bhh, Wh, Wc, Wo, wsh, bg);

  const size_t stage_need = (size_t)OFF_STAGE_BYTES + (size_t)B * STEPS * INP * 4;
  if (ws_size >= stage_need) {
    hipLaunchKernelGGL((lstm_kernel<1>), dim3(NB), dim3(512), 0, stream,
                       z, wsh, bg, bh, bc, bo, out, stage, NB);
    hipLaunchKernelGGL(reorder_kernel, dim3(B / 8), dim3(512), 0, stream,
                       stage, out, NB);
  } else {
    hipLaunchKernelGGL((lstm_kernel<0>), dim3(NB), dim3(512), 0, stream,
                       z, wsh, bg, bh, bc, bo, out, stage, NB);
  }
}

// Round 4
// 867.570 us; speedup vs baseline: 1.0023x; 1.0023x over previous
//
#include <hip/hip_runtime.h>
#include <hip/hip_bf16.h>

#define HID   256
#define NGATE 1024
#define INP   72
#define STEPS 8
#define TB    64
#define LDH   264   // h_lds row stride (bf16 elems): 256 + 8 pad
#define LDX   104   // x_lds row stride: 96 + 8 pad

// ---- weight-stream geometry -------------------------------------------------
// Per wave per step: 96 fragments x 512 bf16 (1 KB) in exact consumption order:
//   f =  0..63 : WHH  (f = kc*8 + q*2 + ct, kc<8)
//   f = 64..87 : WIH  (f = 64 + kc*8 + q*2 + ct, kc<3; K padded to 96, zeros)
//   f = 88..95 : WO   (f = 88 + kc; zero-padded for waves 5..7)
// 96 % RING == 0 -> ring slots realign every step; all offsets compile-time.
#define NFRAG 96
#define RING  12          // wave-private LDS ring slots (12 KB/wave, 96 KB total)
#define WSEQ  49152       // elems per wave sequence = 96*512
// ws layout (bf16 elem offsets)
#define OFF_WH2 393216    // init Wh, packed 16 frags/wave (ct*8+kc)
#define OFF_WC2 458752    // init Wc, same
#define N_ALL   524288    // = 1 MiB of bf16
#define OFF_BG_BYTES    1048576
#define OFF_STAGE_BYTES 1114112

typedef short  s8_t  __attribute__((ext_vector_type(8)));
typedef float  f4_t  __attribute__((ext_vector_type(4)));

static __device__ __forceinline__ unsigned short f2bf(float f) {
  unsigned int u = __float_as_uint(f);
  u = (u + 0x7FFFu + ((u >> 16) & 1u)) >> 16;   // RNE
  return (unsigned short)u;
}
static __device__ __forceinline__ float fast_rcp(float x) {
#if __has_builtin(__builtin_amdgcn_rcpf)
  return __builtin_amdgcn_rcpf(x);
#else
  return 1.f / x;
#endif
}
static __device__ __forceinline__ float sigm(float x) {
  return fast_rcp(1.f + __expf(-x));
}
static __device__ __forceinline__ float tanh_(float x) {
  float t = fminf(-2.f * x, 88.f);
  float e = __expf(t);
  return (1.f - e) * fast_rcp(1.f + e);
}

// ring slot byte layout: slot s at ring_base + s*512 elems (1 KB)
#define RSLOT(F) ((((F) % NFRAG) % RING) * 512)
#define ISSUE_F(F) __builtin_amdgcn_global_load_lds( \
    (const __attribute__((address_space(1))) unsigned int*)(const void*)(seq_l + ((F) % NFRAG) * 512), \
    (__attribute__((address_space(3))) unsigned int*)(void*)(ring_wr + RSLOT(F)), 16, 0, 0)
// steady-state: frags of batch f0 were issued 8 frags (4 batches) earlier;
// ops issued after them = 3 younger batches x 2 = 6  -> vmcnt(6)
#define WAITV6()  asm volatile("s_waitcnt vmcnt(6)" ::: "memory")
// step-boundary batches (f0 = 0,2,4,6): frags were issued BEFORE the y-phase's
// 16 stores -> +16 in the ledger -> vmcnt(22). Step 0 is padded with 16
// duplicate prefetches so the same constant holds; waves 5..7 issue 16 dups
// in place of stores.
#define WAITV22() asm volatile("s_waitcnt vmcnt(22)" ::: "memory")
// raw barrier: drains LDS counters only; ring prefetches stay in flight
#define BAR() do { asm volatile("s_waitcnt lgkmcnt(0)" ::: "memory"); \
                   __builtin_amdgcn_s_barrier(); \
                   asm volatile("" ::: "memory"); } while (0)

__global__ void prep_kernel(const float* __restrict__ Wih, const float* __restrict__ Whh,
                            const float* __restrict__ bih, const float* __restrict__ bhh,
                            const float* __restrict__ Wh, const float* __restrict__ Wc,
                            const float* __restrict__ Wo,
                            unsigned short* __restrict__ wsh, float* __restrict__ bg) {
  int stride = gridDim.x * blockDim.x;
  for (int i = blockIdx.x * blockDim.x + threadIdx.x; i < N_ALL + NGATE; i += stride) {
    if (i < N_ALL) {
      float v = 0.f;
      if (i < OFF_WH2) {
        // per-wave fragment stream
        int w  = i / WSEQ;
        int r  = i - w * WSEQ;
        int f  = r >> 9;
        int e  = r & 511;
        int lane = e >> 3, j = e & 7;
        int lq = lane >> 4, ln = lane & 15;
        int kk = lq * 8 + j;
        if (f < 64) {                         // WHH
          int kc = f >> 3, t = f & 7, q = t >> 1, ct = t & 1;
          int g  = q * 256 + w * 32 + ct * 16 + ln;
          int k  = kc * 32 + kk;
          v = Whh[g * HID + k];
        } else if (f < 88) {                  // WIH (K padded to 96)
          int t2 = f - 64;
          int kc = t2 >> 3, t = t2 & 7, q = t >> 1, ct = t & 1;
          int g  = q * 256 + w * 32 + ct * 16 + ln;
          int k  = kc * 32 + kk;
          v = (k < INP) ? Wih[g * INP + k] : 0.f;
        } else {                              // WO (waves 5..7 padded with 0)
          int kc = f - 88;
          int c  = w * 16 + ln;
          int k  = kc * 32 + kk;
          v = (w < 5 && c < INP) ? Wo[c * HID + k] : 0.f;
        }
      } else {
        // init weights Wh / Wc: 16 frags per wave, fi = ct*8 + kc
        int base = (i < OFF_WC2) ? OFF_WH2 : OFF_WC2;
        const float* Wsrc = (i < OFF_WC2) ? Wh : Wc;
        int jj = i - base;
        int w  = jj >> 13;            // 8192 elems per wave
        int r  = jj & 8191;
        int fi = r >> 9;
        int e  = r & 511;
        int lane = e >> 3, j = e & 7;
        int lq = lane >> 4, ln = lane & 15;
        int ct = fi >> 3, kc = fi & 7;
        int c  = w * 32 + ct * 16 + ln;
        int k  = kc * 32 + lq * 8 + j;
        v = Wsrc[c * HID + k];
      }
      wsh[i] = f2bf(v);
    } else {
      int jb = i - N_ALL;
      bg[jb] = bih[jb] + bhh[jb];
    }
  }
}

// Block: 512 threads = 8 waves, TB=64 batch rows for the whole recurrence.
// Wave w owns gate cols [w*32, w*32+32) in each gate quadrant. Weights stream
// through a wave-private 12-slot LDS ring via global_load_lds: per batch of 2
// frags -> {counted vmcnt wait, 2 ds_read_b128, issue 2 prefetches (lead 8),
// 8 MFMAs}. All waits are compile-time-exact so prefetches never drain; raw
// lgkmcnt-only barriers keep them in flight across phases.
template <int STAGED>
__global__ __launch_bounds__(512, 2) void lstm_kernel(
    const float* __restrict__ z, const unsigned short* __restrict__ wsh,
    const float* __restrict__ bg, const float* __restrict__ bh,
    const float* __restrict__ bc, const float* __restrict__ bo,
    float* __restrict__ out, float* __restrict__ stage, int NB) {
  __shared__ unsigned short h_lds[TB * LDH];
  __shared__ unsigned short x_lds[TB * LDX];
  __shared__ unsigned short ring[8 * RING * 512];   // 96 KB, wave-private slices

  const int tid  = threadIdx.x;
  const int w    = tid >> 6;     // wave 0..7
  const int lane = tid & 63;
  const int lq   = lane >> 4;
  const int ln   = lane & 15;
  const int rb   = blockIdx.x * TB;
  const int colh0 = w * 32 + ln;

  const unsigned short* seq_l   = wsh + w * WSEQ + lane * 8;      // per-lane global src
  unsigned short*       ring_wr = &ring[w * (RING * 512)];        // wave-uniform LDS dst
  const unsigned short* ring_rd = &ring[w * (RING * 512) + lane * 8];

  const unsigned short* wh_l = wsh + OFF_WH2 + w * 8192 + lane * 8;
  const unsigned short* wc_l = wsh + OFF_WC2 + w * 8192 + lane * 8;
  const unsigned short* h_rd = &h_lds[ln * LDH + lq * 8];
  const unsigned short* x_rd = &x_lds[ln * LDX + lq * 8];
  unsigned short*       h_wr = &h_lds[(lq * 4) * LDH + colh0];

  for (int i = tid; i < TB * LDX; i += 512) x_lds[i] = 0;

  // ---------------- init: h = z0@Wh^T + bh, c = z0@Wc^T + bc ----------------
  f4_t acc_h[4][2], acc_c[4][2];
  #pragma unroll
  for (int rt = 0; rt < 4; ++rt)
    #pragma unroll
    for (int ct = 0; ct < 2; ++ct) {
      acc_h[rt][ct] = {0.f, 0.f, 0.f, 0.f};
      acc_c[rt][ct] = {0.f, 0.f, 0.f, 0.f};
    }

  const float* z_l = z + (size_t)(rb + ln) * HID + lq * 8;

  #pragma unroll 2
  for (int kc = 0; kc < 8; ++kc) {
    s8_t a[4];
    #pragma unroll
    for (int rt = 0; rt < 4; ++rt) {
      f4_t v0 = *reinterpret_cast<const f4_t*>(z_l + rt * 16 * HID + kc * 32);
      f4_t v1 = *reinterpret_cast<const f4_t*>(z_l + rt * 16 * HID + kc * 32 + 4);
      s8_t av;
      av[0] = (short)f2bf(v0[0]); av[1] = (short)f2bf(v0[1]);
      av[2] = (short)f2bf(v0[2]); av[3] = (short)f2bf(v0[3]);
      av[4] = (short)f2bf(v1[0]); av[5] = (short)f2bf(v1[1]);
      av[6] = (short)f2bf(v1[2]); av[7] = (short)f2bf(v1[3]);
      a[rt] = av;
    }
    #pragma unroll
    for (int ct = 0; ct < 2; ++ct) {
      s8_t bhf = *reinterpret_cast<const s8_t*>(wh_l + (ct * 8 + kc) * 512);
      s8_t bcf = *reinterpret_cast<const s8_t*>(wc_l + (ct * 8 + kc) * 512);
      #pragma unroll
      for (int rt = 0; rt < 4; ++rt) {
        acc_h[rt][ct] = __builtin_amdgcn_mfma_f32_16x16x32_bf16(a[rt], bhf, acc_h[rt][ct], 0, 0, 0);
        acc_c[rt][ct] = __builtin_amdgcn_mfma_f32_16x16x32_bf16(a[rt], bcf, acc_c[rt][ct], 0, 0, 0);
      }
    }
  }

  // bias loads BEFORE ring prologue so they don't enter the vmcnt ledger
  float biasg[4][2];
  #pragma unroll
  for (int q = 0; q < 4; ++q)
    #pragma unroll
    for (int ct = 0; ct < 2; ++ct)
      biasg[q][ct] = bg[q * 256 + colh0 + ct * 16];
  const float bhv0 = bh[colh0], bhv1 = bh[colh0 + 16];
  const float bcv0 = bc[colh0], bcv1 = bc[colh0 + 16];
  const int colY = w * 16 + ln;            // y col, valid for waves 0..4
  float bov = 0.f;
  if (w < 5 && colY < INP) bov = bo[colY];

  // ring prologue: frags 0..7, plus 16 duplicate prefetches of frag 7 so the
  // step-boundary vmcnt(22) ledger is exact at step 0 (dup = same bytes, safe)
  #pragma unroll
  for (int p = 0; p < 8; ++p) ISSUE_F(p);
  #pragma unroll
  for (int p = 0; p < 16; ++p) ISSUE_F(7);

  float c_reg[4][2][4];
  #pragma unroll
  for (int ct = 0; ct < 2; ++ct) {
    const float bhv = ct ? bhv1 : bhv0;
    const float bcv = ct ? bcv1 : bcv0;
    #pragma unroll
    for (int rt = 0; rt < 4; ++rt)
      #pragma unroll
      for (int r = 0; r < 4; ++r) {
        float hv = acc_h[rt][ct][r] + bhv;
        c_reg[rt][ct][r] = acc_c[rt][ct][r] + bcv;
        h_wr[(rt * 16 + r) * LDH + ct * 16] = f2bf(hv);
      }
  }
  BAR();

  for (int s = 0; s < STEPS; ++s) {
    f4_t acc[4][4][2];                     // [quadrant][row-tile][col-tile]
    #pragma unroll
    for (int q = 0; q < 4; ++q)
      #pragma unroll
      for (int rt = 0; rt < 4; ++rt)
        #pragma unroll
        for (int ct = 0; ct < 2; ++ct) {
          const float b = biasg[q][ct];
          acc[q][rt][ct] = {b, b, b, b};
        }

    // gates += h @ W_hh^T   (K = 256) : frags 0..63
    #pragma unroll
    for (int kc = 0; kc < 8; ++kc) {
      s8_t a[4];
      #pragma unroll
      for (int rt = 0; rt < 4; ++rt)
        a[rt] = *reinterpret_cast<const s8_t*>(h_rd + rt * 16 * LDH + kc * 32);
      #pragma unroll
      for (int q = 0; q < 4; ++q) {
        const int f0 = kc * 8 + q * 2;     // frags f0, f0+1 (ct = 0,1)
        if (f0 < 8) { WAITV22(); } else { WAITV6(); }
        s8_t b0 = *reinterpret_cast<const s8_t*>(ring_rd + RSLOT(f0));
        s8_t b1 = *reinterpret_cast<const s8_t*>(ring_rd + RSLOT(f0 + 1));
        ISSUE_F(f0 + 8); ISSUE_F(f0 + 9);
        #pragma unroll
        for (int rt = 0; rt < 4; ++rt) {
          acc[q][rt][0] = __builtin_amdgcn_mfma_f32_16x16x32_bf16(a[rt], b0, acc[q][rt][0], 0, 0, 0);
          acc[q][rt][1] = __builtin_amdgcn_mfma_f32_16x16x32_bf16(a[rt], b1, acc[q][rt][1], 0, 0, 0);
        }
      }
    }
    // gates += x @ W_ih^T   (K = 96 padded) : frags 64..87
    #pragma unroll
    for (int kc = 0; kc < 3; ++kc) {
      s8_t a[4];
      #pragma unroll
      for (int rt = 0; rt < 4; ++rt)
        a[rt] = *reinterpret_cast<const s8_t*>(x_rd + rt * 16 * LDX + kc * 32);
      #pragma unroll
      for (int q = 0; q < 4; ++q) {
        const int f0 = 64 + kc * 8 + q * 2;
        WAITV6();
        s8_t b0 = *reinterpret_cast<const s8_t*>(ring_rd + RSLOT(f0));
        s8_t b1 = *reinterpret_cast<const s8_t*>(ring_rd + RSLOT(f0 + 1));
        ISSUE_F(f0 + 8); ISSUE_F(f0 + 9);
        #pragma unroll
        for (int rt = 0; rt < 4; ++rt) {
          acc[q][rt][0] = __builtin_amdgcn_mfma_f32_16x16x32_bf16(a[rt], b0, acc[q][rt][0], 0, 0, 0);
          acc[q][rt][1] = __builtin_amdgcn_mfma_f32_16x16x32_bf16(a[rt], b1, acc[q][rt][1], 0, 0, 0);
        }
      }
    }
    BAR();   // all h_lds/x_lds reads done

    // lane-local LSTM cell update; write new h (bf16) to LDS
    #pragma unroll
    for (int rt = 0; rt < 4; ++rt)
      #pragma unroll
      for (int ct = 0; ct < 2; ++ct)
        #pragma unroll
        for (int r = 0; r < 4; ++r) {
          float iv = sigm(acc[0][rt][ct][r]);
          float fv = sigm(acc[1][rt][ct][r]);
          float gv = tanh_(acc[2][rt][ct][r]);
          float ov = sigm(acc[3][rt][ct][r]);
          float cn = fv * c_reg[rt][ct][r] + iv * gv;
          c_reg[rt][ct][r] = cn;
          float hv = ov * tanh_(cn);
          h_wr[(rt * 16 + r) * LDH + ct * 16] = f2bf(hv);
        }
    BAR();   // new h visible to all waves

    // y = sigmoid(h_new @ Wo^T + bo) : frags 88..95 (waves 5..7 stream pads;
    // their ISSUEs keep the ring schedule aligned, data never read)
    {
      f4_t accy[4];
      #pragma unroll
      for (int rt = 0; rt < 4; ++rt) accy[rt] = {bov, bov, bov, bov};
      #pragma unroll
      for (int b2 = 0; b2 < 4; ++b2) {
        const int f0 = 88 + b2 * 2;        // kc' = b2*2, b2*2+1
        WAITV6();
        s8_t b0 = *reinterpret_cast<const s8_t*>(ring_rd + RSLOT(f0));
        s8_t b1 = *reinterpret_cast<const s8_t*>(ring_rd + RSLOT(f0 + 1));
        ISSUE_F(f0 + 8); ISSUE_F(f0 + 9);  // wraps to next step's frags 0..7
        if (w < 5) {
          const int k0 = b2 * 2, k1 = b2 * 2 + 1;
          #pragma unroll
          for (int rt = 0; rt < 4; ++rt) {
            s8_t a0 = *reinterpret_cast<const s8_t*>(h_rd + rt * 16 * LDH + k0 * 32);
            accy[rt] = __builtin_amdgcn_mfma_f32_16x16x32_bf16(a0, b0, accy[rt], 0, 0, 0);
            s8_t a1 = *reinterpret_cast<const s8_t*>(h_rd + rt * 16 * LDH + k1 * 32);
            accy[rt] = __builtin_amdgcn_mfma_f32_16x16x32_bf16(a1, b1, accy[rt], 0, 0, 0);
          }
        }
      }
      if (w < 5 && colY < INP) {
        float* st_base;
        if (STAGED) {
          st_base = stage + (((size_t)s * NB + blockIdx.x) * TB + lq * 4) * INP + colY;
        } else {
          st_base = out + (size_t)(rb + lq * 4) * (STEPS * INP) + s * INP + colY;
        }
        unsigned short* x_wr = &x_lds[(lq * 4) * LDX + colY];
        #pragma unroll
        for (int rt = 0; rt < 4; ++rt)
          #pragma unroll
          for (int r = 0; r < 4; ++r) {
            float yv = sigm(accy[rt][r]);
            if (STAGED) {
              st_base[(size_t)(rt * 16 + r) * INP] = yv;
            } else {
              st_base[(size_t)(rt * 16 + r) * (STEPS * INP)] = yv;
            }
            x_wr[(rt * 16 + r) * LDX] = f2bf(yv);
          }
      }
      if (w >= 5) {
        // no stores on these waves: 16 duplicate prefetches keep the
        // per-wave vmcnt ledger identical to storing waves (dup = same bytes)
        #pragma unroll
        for (int p = 0; p < 16; ++p) ISSUE_F(95);
      }
    }
    BAR();   // x_lds writes done before next step's reads
  }
}

// stage[((s*NB + b)*TB + r)*72 + c]  ->  out[(b*TB + r)*576 + s*72 + c]
__global__ __launch_bounds__(512) void reorder_kernel(
    const float* __restrict__ stage, float* __restrict__ out, int NB) {
  const int lane = threadIdx.x & 63;
  const int row  = blockIdx.x * 8 + (threadIdx.x >> 6);   // global batch row
  const int b    = row >> 6;          // TB=64
  const int r    = row & 63;
  #pragma unroll
  for (int i = lane; i < STEPS * INP; i += 64) {
    int s = i / INP;
    int c = i - s * INP;
    out[(size_t)row * (STEPS * INP) + i] =
        stage[(((size_t)s * NB + b) * TB + r) * INP + c];
  }
}

extern "C" void kernel_launch(void* const* d_in, const int* in_sizes, int n_in,
                              void* d_out, int out_size, void* d_ws, size_t ws_size,
                              hipStream_t stream) {
  const float* z   = (const float*)d_in[0];
  const float* Wih = (const float*)d_in[1];
  const float* Whh = (const float*)d_in[2];
  const float* bih = (const float*)d_in[3];
  const float* bhh = (const float*)d_in[4];
  const float* Wh  = (const float*)d_in[5];
  const float* bh  = (const float*)d_in[6];
  const float* Wc  = (const float*)d_in[7];
  const float* bc  = (const float*)d_in[8];
  const float* Wo  = (const float*)d_in[9];
  const float* bo  = (const float*)d_in[10];
  float* out = (float*)d_out;

  unsigned short* wsh = (unsigned short*)d_ws;
  float* bg    = (float*)((char*)d_ws + OFF_BG_BYTES);
  float* stage = (float*)((char*)d_ws + OFF_STAGE_BYTES);

  const int B  = in_sizes[0] / HID;   // 32768
  const int NB = B / TB;              // 512

  hipLaunchKernelGGL(prep_kernel, dim3(512), dim3(256), 0, stream,
                     Wih, Whh, bih, bhh, Wh, Wc, Wo, wsh, bg);

  const size_t stage_need = (size_t)OFF_STAGE_BYTES + (size_t)B * STEPS * INP * 4;
  if (ws_size >= stage_need) {
    hipLaunchKernelGGL((lstm_kernel<1>), dim3(NB), dim3(512), 0, stream,
                       z, wsh, bg, bh, bc, bo, out, stage, NB);
    hipLaunchKernelGGL(reorder_kernel, dim3(B / 8), dim3(512), 0, stream,
                       stage, out, NB);
  } else {
    hipLaunchKernelGGL((lstm_kernel<0>), dim3(NB), dim3(512), 0, stream,
                       z, wsh, bg, bh, bc, bo, out, stage, NB);
  }
}

// Round 5
// 556.970 us; speedup vs baseline: 1.5612x; 1.5577x over previous
//
#include <hip/hip_runtime.h>
#include <hip/hip_bf16.h>

#define HID   256
#define NGATE 1024
#define INP   72
#define STEPS 8
#define TB    64
#define NTHR  1024    // 16 waves; each wave owns 16 gate-cols x all 64 rows
#define LDH   264     // h_lds row stride (bf16 elems): 256 + 8 pad
#define LDX   104     // x_lds row stride: 96 + 8 pad

// ---- weight-stream geometry -------------------------------------------------
// Per wave (of 16) per step: 52 fragments x 512 bf16 (1 KB), consumption order:
//   f =  0..31 : WHH  (f = kc*4 + q, kc<8)
//   f = 32..43 : WIH  (f = 32 + kc*4 + q, kc<3; K padded to 96 with zeros)
//   f = 44..51 : WO   (f = 44 + kc; zero for waves 5..15)
// Per-wave stream stride padded to 32768 elems (frags 52..63 zero, unused).
#define WSEQ2 32768
#define OFF_WHI 524288    // init Wh: wave w, frag kc -> OFF_WHI + w*4096 + kc*512
#define OFF_WCI 589824    // init Wc: same layout
#define N_ALL   655360
#define OFF_BG_BYTES    1310720
#define OFF_STAGE_BYTES 1314816

typedef short  s8_t  __attribute__((ext_vector_type(8)));
typedef float  f4_t  __attribute__((ext_vector_type(4)));

static __device__ __forceinline__ unsigned short f2bf(float f) {
  unsigned int u = __float_as_uint(f);
  u = (u + 0x7FFFu + ((u >> 16) & 1u)) >> 16;   // RNE
  return (unsigned short)u;
}
static __device__ __forceinline__ float fast_rcp(float x) {
#if __has_builtin(__builtin_amdgcn_rcpf)
  return __builtin_amdgcn_rcpf(x);
#else
  return 1.f / x;
#endif
}
static __device__ __forceinline__ float sigm(float x) {
  return fast_rcp(1.f + __expf(-x));
}
static __device__ __forceinline__ float tanh_(float x) {
  float t = fminf(-2.f * x, 88.f);
  float e = __expf(t);
  return (1.f - e) * fast_rcp(1.f + e);
}

__global__ void prep_kernel(const float* __restrict__ Wih, const float* __restrict__ Whh,
                            const float* __restrict__ bih, const float* __restrict__ bhh,
                            const float* __restrict__ Wh, const float* __restrict__ Wc,
                            const float* __restrict__ Wo,
                            unsigned short* __restrict__ wsh, float* __restrict__ bg) {
  int stride = gridDim.x * blockDim.x;
  for (int i = blockIdx.x * blockDim.x + threadIdx.x; i < N_ALL + NGATE; i += stride) {
    if (i < N_ALL) {
      float v = 0.f;
      if (i < OFF_WHI) {
        // per-wave fragment stream (16 waves x 64 frag slots, 52 used)
        int w  = i >> 15;           // wave 0..15
        int r  = i & 32767;
        int f  = r >> 9;            // frag slot 0..63
        int e  = r & 511;
        int lane = e >> 3, j = e & 7;
        int lq = lane >> 4, ln = lane & 15;
        int kk = lq * 8 + j;
        if (f < 32) {                         // WHH
          int kc = f >> 2, q = f & 3;
          int g  = q * 256 + w * 16 + ln;
          int k  = kc * 32 + kk;
          v = Whh[g * HID + k];
        } else if (f < 44) {                  // WIH (K padded to 96)
          int t  = f - 32;
          int kc = t >> 2, q = t & 3;
          int g  = q * 256 + w * 16 + ln;
          int k  = kc * 32 + kk;
          v = (k < INP) ? Wih[g * INP + k] : 0.f;
        } else if (f < 52) {                  // WO (only waves 0..4 real)
          int kc = f - 44;
          int c  = w * 16 + ln;
          int k  = kc * 32 + kk;
          v = (w < 5 && c < INP) ? Wo[c * HID + k] : 0.f;
        }
        // f 52..63: zero pad
      } else {
        // init weights Wh / Wc: per wave 8 frags (kc)
        int base = (i < OFF_WCI) ? OFF_WHI : OFF_WCI;
        const float* Wsrc = (i < OFF_WCI) ? Wh : Wc;
        int jj = i - base;
        int w  = jj >> 12;          // 4096 elems per wave
        int r  = jj & 4095;
        int kc = r >> 9;
        int e  = r & 511;
        int lane = e >> 3, j = e & 7;
        int lq = lane >> 4, ln = lane & 15;
        int c  = w * 16 + ln;
        int k  = kc * 32 + lq * 8 + j;
        v = Wsrc[c * HID + k];
      }
      wsh[i] = f2bf(v);
    } else {
      int jb = i - N_ALL;
      bg[jb] = bih[jb] + bhh[jb];
    }
  }
}

// Block: 1024 threads = 16 waves, TB=64 batch rows for the whole recurrence.
// Wave w owns hidden cols [w*16, w*16+16) -> for each gate quadrant q, the
// gate rows q*256 + those cols. Per-wave accumulator = acc[4q][4rt] (64 f32),
// c-state 16 f32 -> combined regs fit the 128 cap of 4 waves/SIMD, giving
// 16 waves/CU (2x the previous occupancy) for latency hiding. Dataflow and
// numerics identical to the verified 2-wave/SIMD version.
template <int STAGED>
__global__ __launch_bounds__(NTHR, 4) void lstm_kernel(
    const float* __restrict__ z, const unsigned short* __restrict__ wsh,
    const float* __restrict__ bg, const float* __restrict__ bh,
    const float* __restrict__ bc, const float* __restrict__ bo,
    float* __restrict__ out, float* __restrict__ stage, int NB) {
  __shared__ unsigned short h_lds[TB * LDH];
  __shared__ unsigned short x_lds[TB * LDX];

  const int tid  = threadIdx.x;
  const int w    = tid >> 6;     // wave 0..15
  const int lane = tid & 63;
  const int lq   = lane >> 4;
  const int ln   = lane & 15;
  const int rb   = blockIdx.x * TB;
  const int colh0 = w * 16 + ln; // wave's 16 hidden cols

  // packed fragment bases: uniform-per-wave + lane*8 elems (16B/lane)
  const unsigned short* wst = wsh + w * WSEQ2 + lane * 8;           // step stream
  const unsigned short* whi = wsh + OFF_WHI + w * 4096 + lane * 8;  // init Wh
  const unsigned short* wci = wsh + OFF_WCI + w * 4096 + lane * 8;  // init Wc
  const unsigned short* h_rd = &h_lds[ln * LDH + lq * 8];
  const unsigned short* x_rd = &x_lds[ln * LDX + lq * 8];
  unsigned short*       h_wr = &h_lds[(lq * 4) * LDH + colh0];

  for (int i = tid; i < TB * LDX; i += NTHR) x_lds[i] = 0;

  // ---------------- init: h = z0@Wh^T + bh, c = z0@Wc^T + bc ----------------
  f4_t acc_h[4], acc_c[4];
  #pragma unroll
  for (int rt = 0; rt < 4; ++rt) {
    acc_h[rt] = {0.f, 0.f, 0.f, 0.f};
    acc_c[rt] = {0.f, 0.f, 0.f, 0.f};
  }

  const float* z_l = z + (size_t)(rb + ln) * HID + lq * 8;

  #pragma unroll 2
  for (int kc = 0; kc < 8; ++kc) {
    s8_t a[4];
    #pragma unroll
    for (int rt = 0; rt < 4; ++rt) {
      f4_t v0 = *reinterpret_cast<const f4_t*>(z_l + rt * 16 * HID + kc * 32);
      f4_t v1 = *reinterpret_cast<const f4_t*>(z_l + rt * 16 * HID + kc * 32 + 4);
      s8_t av;
      av[0] = (short)f2bf(v0[0]); av[1] = (short)f2bf(v0[1]);
      av[2] = (short)f2bf(v0[2]); av[3] = (short)f2bf(v0[3]);
      av[4] = (short)f2bf(v1[0]); av[5] = (short)f2bf(v1[1]);
      av[6] = (short)f2bf(v1[2]); av[7] = (short)f2bf(v1[3]);
      a[rt] = av;
    }
    s8_t bhf = *reinterpret_cast<const s8_t*>(whi + kc * 512);
    s8_t bcf = *reinterpret_cast<const s8_t*>(wci + kc * 512);
    #pragma unroll
    for (int rt = 0; rt < 4; ++rt) {
      acc_h[rt] = __builtin_amdgcn_mfma_f32_16x16x32_bf16(a[rt], bhf, acc_h[rt], 0, 0, 0);
      acc_c[rt] = __builtin_amdgcn_mfma_f32_16x16x32_bf16(a[rt], bcf, acc_c[rt], 0, 0, 0);
    }
  }

  float c_reg[4][4];
  {
    const float bhv = bh[colh0];
    const float bcv = bc[colh0];
    #pragma unroll
    for (int rt = 0; rt < 4; ++rt)
      #pragma unroll
      for (int r = 0; r < 4; ++r) {
        float hv = acc_h[rt][r] + bhv;
        c_reg[rt][r] = acc_c[rt][r] + bcv;
        h_wr[(rt * 16 + r) * LDH] = f2bf(hv);
      }
  }
  __syncthreads();

  float biasg[4];
  #pragma unroll
  for (int q = 0; q < 4; ++q)
    biasg[q] = bg[q * 256 + colh0];

  float bov = 0.f;
  if (w < 5 && colh0 < INP) bov = bo[colh0];   // y col == colh0 for waves 0..4

  for (int s = 0; s < STEPS; ++s) {
    f4_t acc[4][4];                     // [quadrant][row-tile]
    #pragma unroll
    for (int q = 0; q < 4; ++q)
      #pragma unroll
      for (int rt = 0; rt < 4; ++rt) {
        const float b = biasg[q];
        acc[q][rt] = {b, b, b, b};
      }

    // gates += h @ W_hh^T   (K = 256) : frags 0..31
    #pragma unroll 2
    for (int kc = 0; kc < 8; ++kc) {
      s8_t a[4];
      #pragma unroll
      for (int rt = 0; rt < 4; ++rt)
        a[rt] = *reinterpret_cast<const s8_t*>(h_rd + rt * 16 * LDH + kc * 32);
      #pragma unroll
      for (int q = 0; q < 4; ++q) {
        s8_t bfr = *reinterpret_cast<const s8_t*>(wst + (kc * 4 + q) * 512);
        #pragma unroll
        for (int rt = 0; rt < 4; ++rt)
          acc[q][rt] = __builtin_amdgcn_mfma_f32_16x16x32_bf16(a[rt], bfr, acc[q][rt], 0, 0, 0);
      }
    }
    // gates += x @ W_ih^T   (K = 96 padded) : frags 32..43
    #pragma unroll
    for (int kc = 0; kc < 3; ++kc) {
      s8_t a[4];
      #pragma unroll
      for (int rt = 0; rt < 4; ++rt)
        a[rt] = *reinterpret_cast<const s8_t*>(x_rd + rt * 16 * LDX + kc * 32);
      #pragma unroll
      for (int q = 0; q < 4; ++q) {
        s8_t bfr = *reinterpret_cast<const s8_t*>(wst + (32 + kc * 4 + q) * 512);
        #pragma unroll
        for (int rt = 0; rt < 4; ++rt)
          acc[q][rt] = __builtin_amdgcn_mfma_f32_16x16x32_bf16(a[rt], bfr, acc[q][rt], 0, 0, 0);
      }
    }
    __syncthreads();   // all h_lds/x_lds reads done

    // lane-local LSTM cell update; write new h (bf16) to LDS
    #pragma unroll
    for (int rt = 0; rt < 4; ++rt)
      #pragma unroll
      for (int r = 0; r < 4; ++r) {
        float iv = sigm(acc[0][rt][r]);
        float fv = sigm(acc[1][rt][r]);
        float gv = tanh_(acc[2][rt][r]);
        float ov = sigm(acc[3][rt][r]);
        float cn = fv * c_reg[rt][r] + iv * gv;
        c_reg[rt][r] = cn;
        float hv = ov * tanh_(cn);
        h_wr[(rt * 16 + r) * LDH] = f2bf(hv);
      }
    __syncthreads();   // new h visible to all waves

    // y = sigmoid(h_new @ Wo^T + bo); waves 0..4 own the 5 y col-tiles
    if (w < 5) {
      f4_t accy[4];
      #pragma unroll
      for (int rt = 0; rt < 4; ++rt) accy[rt] = {bov, bov, bov, bov};
      #pragma unroll 2
      for (int kc = 0; kc < 8; ++kc) {
        s8_t bfr = *reinterpret_cast<const s8_t*>(wst + (44 + kc) * 512);
        #pragma unroll
        for (int rt = 0; rt < 4; ++rt) {
          s8_t a = *reinterpret_cast<const s8_t*>(h_rd + rt * 16 * LDH + kc * 32);
          accy[rt] = __builtin_amdgcn_mfma_f32_16x16x32_bf16(a, bfr, accy[rt], 0, 0, 0);
        }
      }
      if (colh0 < INP) {
        float* st_base;
        if (STAGED) {
          st_base = stage + (((size_t)s * NB + blockIdx.x) * TB + lq * 4) * INP + colh0;
        } else {
          st_base = out + (size_t)(rb + lq * 4) * (STEPS * INP) + s * INP + colh0;
        }
        unsigned short* x_wr = &x_lds[(lq * 4) * LDX + colh0];
        #pragma unroll
        for (int rt = 0; rt < 4; ++rt)
          #pragma unroll
          for (int r = 0; r < 4; ++r) {
            float yv = sigm(accy[rt][r]);
            if (STAGED) {
              st_base[(size_t)(rt * 16 + r) * INP] = yv;
            } else {
              st_base[(size_t)(rt * 16 + r) * (STEPS * INP)] = yv;
            }
            x_wr[(rt * 16 + r) * LDX] = f2bf(yv);
          }
      }
    }
    __syncthreads();   // x_lds writes done before next step's reads
  }
}

// stage[((s*NB + b)*TB + r)*72 + c]  ->  out[(b*TB + r)*576 + s*72 + c]
__global__ __launch_bounds__(512) void reorder_kernel(
    const float* __restrict__ stage, float* __restrict__ out, int NB) {
  const int lane = threadIdx.x & 63;
  const int row  = blockIdx.x * 8 + (threadIdx.x >> 6);   // global batch row
  const int b    = row >> 6;          // TB=64
  const int r    = row & 63;
  #pragma unroll
  for (int i = lane; i < STEPS * INP; i += 64) {
    int s = i / INP;
    int c = i - s * INP;
    out[(size_t)row * (STEPS * INP) + i] =
        stage[(((size_t)s * NB + b) * TB + r) * INP + c];
  }
}

extern "C" void kernel_launch(void* const* d_in, const int* in_sizes, int n_in,
                              void* d_out, int out_size, void* d_ws, size_t ws_size,
                              hipStream_t stream) {
  const float* z   = (const float*)d_in[0];
  const float* Wih = (const float*)d_in[1];
  const float* Whh = (const float*)d_in[2];
  const float* bih = (const float*)d_in[3];
  const float* bhh = (const float*)d_in[4];
  const float* Wh  = (const float*)d_in[5];
  const float* bh  = (const float*)d_in[6];
  const float* Wc  = (const float*)d_in[7];
  const float* bc  = (const float*)d_in[8];
  const float* Wo  = (const float*)d_in[9];
  const float* bo  = (const float*)d_in[10];
  float* out = (float*)d_out;

  unsigned short* wsh = (unsigned short*)d_ws;
  float* bg    = (float*)((char*)d_ws + OFF_BG_BYTES);
  float* stage = (float*)((char*)d_ws + OFF_STAGE_BYTES);

  const int B  = in_sizes[0] / HID;   // 32768
  const int NB = B / TB;              // 512

  hipLaunchKernelGGL(prep_kernel, dim3(512), dim3(256), 0, stream,
                     Wih, Whh, bih, bhh, Wh, Wc, Wo, wsh, bg);

  const size_t stage_need = (size_t)OFF_STAGE_BYTES + (size_t)B * STEPS * INP * 4;
  if (ws_size >= stage_need) {
    hipLaunchKernelGGL((lstm_kernel<1>), dim3(NB), dim3(NTHR), 0, stream,
                       z, wsh, bg, bh, bc, bo, out, stage, NB);
    hipLaunchKernelGGL(reorder_kernel, dim3(B / 8), dim3(512), 0, stream,
                       stage, out, NB);
  } else {
    hipLaunchKernelGGL((lstm_kernel<0>), dim3(NB), dim3(NTHR), 0, stream,
                       z, wsh, bg, bh, bc, bo, out, stage, NB);
  }
}